// Round 1
// baseline (541.126 us; speedup 1.0000x reference)
//
#include <hip/hip_runtime.h>
#include <hip/hip_bf16.h>

#define B_DIM 4096
#define UNITS_DIM 2048
#define K_DIM 4096   // INP + UNITS concatenated
#define M_DIM 8192   // 4 gates * UNITS, interleaved n = u*4 + g

typedef __bf16 bf16x8 __attribute__((ext_vector_type(8)));
typedef float f32x4 __attribute__((ext_vector_type(4)));

#define AS1C(p) ((const __attribute__((address_space(1))) void*)(p))
#define AS3(p)  ((__attribute__((address_space(3))) void*)(p))

__device__ __forceinline__ float fast_sigmoid(float x) {
    return 1.0f / (1.0f + __expf(-x));
}
__device__ __forceinline__ float fast_tanh(float x) {
    return 2.0f / (1.0f + __expf(-2.0f * x)) - 1.0f;
}

// ---------------------------------------------------------------------------
// Kernel 1: Abf[b][k] = bf16( k<2048 ? x[b][k] : pre_h[b][k-2048] )
// 4096 x 4096, 8 elems/thread, fully coalesced (float4 x2 in, uint4 out).
// ---------------------------------------------------------------------------
__global__ void convert_act(const float* __restrict__ pre_h,
                            const float* __restrict__ x,
                            __hip_bfloat16* __restrict__ Abf) {
    const long long idx = (long long)blockIdx.x * blockDim.x + threadIdx.x;
    const long long e = idx * 8;                  // flat element index into Abf
    const int b = (int)(e >> 12);                 // / 4096
    const int k = (int)(e & 4095);
    const float* src = (k < UNITS_DIM)
        ? (x + (long long)b * UNITS_DIM + k)
        : (pre_h + (long long)b * UNITS_DIM + (k - UNITS_DIM));
    float4 f0 = ((const float4*)src)[0];
    float4 f1 = ((const float4*)src)[1];
    union { __hip_bfloat16 h[8]; uint4 u4; } p;
    p.h[0] = __float2bfloat16(f0.x); p.h[1] = __float2bfloat16(f0.y);
    p.h[2] = __float2bfloat16(f0.z); p.h[3] = __float2bfloat16(f0.w);
    p.h[4] = __float2bfloat16(f1.x); p.h[5] = __float2bfloat16(f1.y);
    p.h[6] = __float2bfloat16(f1.z); p.h[7] = __float2bfloat16(f1.w);
    *(uint4*)(Abf + e) = p.u4;
}

// ---------------------------------------------------------------------------
// Kernel 2: Bbf[n][k], n = u*4+g:  k<2048 ? W[g][u][k] : U[g][u][k-2048]
// 8192 x 4096. Gate-interleaved rows so MFMA C/D frag holds all 4 gates/lane.
// ---------------------------------------------------------------------------
__global__ void convert_wu(const float* __restrict__ W,
                           const float* __restrict__ U,
                           __hip_bfloat16* __restrict__ Bbf) {
    const long long idx = (long long)blockIdx.x * blockDim.x + threadIdx.x;
    const long long e = idx * 8;
    const int n = (int)(e >> 12);
    const int k = (int)(e & 4095);
    const int u = n >> 2;
    const int g = n & 3;
    const float* src = (k < UNITS_DIM)
        ? (W + ((long long)g * UNITS_DIM + u) * UNITS_DIM + k)
        : (U + ((long long)g * UNITS_DIM + u) * UNITS_DIM + (k - UNITS_DIM));
    float4 f0 = ((const float4*)src)[0];
    float4 f1 = ((const float4*)src)[1];
    union { __hip_bfloat16 h[8]; uint4 u4; } p;
    p.h[0] = __float2bfloat16(f0.x); p.h[1] = __float2bfloat16(f0.y);
    p.h[2] = __float2bfloat16(f0.z); p.h[3] = __float2bfloat16(f0.w);
    p.h[4] = __float2bfloat16(f1.x); p.h[5] = __float2bfloat16(f1.y);
    p.h[6] = __float2bfloat16(f1.z); p.h[7] = __float2bfloat16(f1.w);
    *(uint4*)(Bbf + e) = p.u4;
}

// ---------------------------------------------------------------------------
// Kernel 3: m97-style bt-GEMM  C'[m][nb] = sum_k Wc[m][k] * Ac[nb][k]
//   M=8192 (gate-interleaved), N=4096 (batch), K=4096, fused LSTM epilogue.
// 128x128 tile, BK=64, 256 threads = 4 waves (2x2 of 64x64), 16x16x32 MFMA.
// Per acc frag, lane holds col=lane&15 (batch b), rows quad*4+{0..3} = gates
// i,f,o,n~ of a single u  ->  epilogue entirely in registers.
// ---------------------------------------------------------------------------
__global__ __launch_bounds__(256, 3) void lstm_gemm(
    const __hip_bfloat16* __restrict__ Wc,   // 8192 x 4096 (A operand)
    const __hip_bfloat16* __restrict__ Ac,   // 4096 x 4096 (B operand)
    const float* __restrict__ pre_c,         // 4096 x 2048
    float* __restrict__ out)                 // (2, 4096, 2048)
{
    __shared__ __hip_bfloat16 As[128 * 64];  // weight tile
    __shared__ __hip_bfloat16 Bs[128 * 64];  // activation tile

    const int tid  = threadIdx.x;
    const int lane = tid & 63;
    const int wave = tid >> 6;
    const int m_base = blockIdx.x * 128;     // gridDim.x = 64
    const int n_base = blockIdx.y * 128;     // gridDim.y = 32
    const int wm = (wave >> 1) * 64;
    const int wn = (wave & 1) * 64;
    const int l15 = lane & 15;
    const int lq  = lane >> 4;

    f32x4 acc[4][4] = {};

    // staging pattern: thread t handles 16B; row = t/8 (+32 per round), col = (t&7)*8
    const int srow = tid >> 3;
    const int scol = (tid & 7) * 8;
    const __hip_bfloat16* wg = Wc + (size_t)(m_base + srow) * K_DIM + scol;
    const __hip_bfloat16* ag = Ac + (size_t)(n_base + srow) * K_DIM + scol;

    for (int k0 = 0; k0 < K_DIM; k0 += 64) {
#pragma unroll
        for (int r = 0; r < 4; ++r) {
            __builtin_amdgcn_global_load_lds(
                AS1C(wg + (size_t)(r * 32) * K_DIM + k0),
                AS3(As + r * 2048 + tid * 8), 16, 0, 0);
            __builtin_amdgcn_global_load_lds(
                AS1C(ag + (size_t)(r * 32) * K_DIM + k0),
                AS3(Bs + r * 2048 + tid * 8), 16, 0, 0);
        }
        __syncthreads();
#pragma unroll
        for (int ki = 0; ki < 2; ++ki) {
            bf16x8 af[4], bfr[4];
#pragma unroll
            for (int mi = 0; mi < 4; ++mi)
                af[mi] = *(const bf16x8*)(As + (wm + mi * 16 + l15) * 64 + ki * 32 + lq * 8);
#pragma unroll
            for (int ni = 0; ni < 4; ++ni)
                bfr[ni] = *(const bf16x8*)(Bs + (wn + ni * 16 + l15) * 64 + ki * 32 + lq * 8);
#pragma unroll
            for (int mi = 0; mi < 4; ++mi)
#pragma unroll
                for (int ni = 0; ni < 4; ++ni)
                    acc[mi][ni] = __builtin_amdgcn_mfma_f32_16x16x32_bf16(
                        af[mi], bfr[ni], acc[mi][ni], 0, 0, 0);
        }
        __syncthreads();
    }

    // Fused LSTM epilogue — each lane's frag = (i,f,o,n~) for one (b,u)
#pragma unroll
    for (int mi = 0; mi < 4; ++mi) {
        const int u = ((m_base + wm + mi * 16) >> 2) + lq;   // m = base + lq*4 + reg
#pragma unroll
        for (int ni = 0; ni < 4; ++ni) {
            const int b = n_base + wn + ni * 16 + l15;
            f32x4 gv = acc[mi][ni];
            float i_t = fast_sigmoid(gv[0]);
            float f_t = fast_sigmoid(gv[1]);
            float o_t = fast_sigmoid(gv[2]);
            float n_t = fast_tanh(gv[3]);
            float pc  = pre_c[(size_t)b * UNITS_DIM + u];
            float c   = f_t * pc + i_t * n_t;
            float h   = o_t * fast_tanh(c);
            out[(size_t)b * UNITS_DIM + u] = h;
            out[(size_t)B_DIM * UNITS_DIM + (size_t)b * UNITS_DIM + u] = c;
        }
    }
}

extern "C" void kernel_launch(void* const* d_in, const int* in_sizes, int n_in,
                              void* d_out, int out_size, void* d_ws, size_t ws_size,
                              hipStream_t stream) {
    const float* pre_layer = (const float*)d_in[0];   // (2, 4096, 2048)
    const float* x         = (const float*)d_in[1];   // (4096, 2048)
    const float* W         = (const float*)d_in[2];   // (4, 2048, 2048)
    const float* U         = (const float*)d_in[3];   // (4, 2048, 2048)
    float* out = (float*)d_out;

    const float* pre_h = pre_layer;
    const float* pre_c = pre_layer + (size_t)B_DIM * UNITS_DIM;

    __hip_bfloat16* Abf = (__hip_bfloat16*)d_ws;                       // 4096x4096 bf16 = 32 MiB
    __hip_bfloat16* Bbf = (__hip_bfloat16*)((char*)d_ws +
                          (size_t)B_DIM * K_DIM * sizeof(__hip_bfloat16)); // 8192x4096 bf16 = 64 MiB

    // 4096*4096/8/256 = 8192 blocks
    convert_act<<<8192, 256, 0, stream>>>(pre_h, x, Abf);
    // 8192*4096/8/256 = 16384 blocks
    convert_wu<<<16384, 256, 0, stream>>>(W, U, Bbf);

    dim3 grid(M_DIM / 128, B_DIM / 128);   // (64, 32)
    lstm_gemm<<<grid, 256, 0, stream>>>(Bbf, Abf, pre_c, out);
}

// Round 2
// 523.458 us; speedup vs baseline: 1.0338x; 1.0338x over previous
//
#include <hip/hip_runtime.h>
#include <hip/hip_bf16.h>

#define B_DIM 4096
#define UNITS_DIM 2048
#define K_DIM 4096   // INP + UNITS concatenated
#define M_DIM 8192   // 4 gates * UNITS, interleaved n = u*4 + g

typedef __bf16 bf16x8 __attribute__((ext_vector_type(8)));
typedef float f32x4 __attribute__((ext_vector_type(4)));

#define AS1C(p) ((const __attribute__((address_space(1))) void*)(p))
#define AS3(p)  ((__attribute__((address_space(3))) void*)(p))

__device__ __forceinline__ float fast_sigmoid(float x) {
    return 1.0f / (1.0f + __expf(-x));
}
__device__ __forceinline__ float fast_tanh(float x) {
    return 2.0f / (1.0f + __expf(-2.0f * x)) - 1.0f;
}

// ---------------------------------------------------------------------------
// Kernel 1: Abf[b][k] = bf16( k<2048 ? x[b][k] : pre_h[b][k-2048] )
// ---------------------------------------------------------------------------
__global__ void convert_act(const float* __restrict__ pre_h,
                            const float* __restrict__ x,
                            __hip_bfloat16* __restrict__ Abf) {
    const long long idx = (long long)blockIdx.x * blockDim.x + threadIdx.x;
    const long long e = idx * 8;
    const int b = (int)(e >> 12);
    const int k = (int)(e & 4095);
    const float* src = (k < UNITS_DIM)
        ? (x + (long long)b * UNITS_DIM + k)
        : (pre_h + (long long)b * UNITS_DIM + (k - UNITS_DIM));
    float4 f0 = ((const float4*)src)[0];
    float4 f1 = ((const float4*)src)[1];
    union { __hip_bfloat16 h[8]; uint4 u4; } p;
    p.h[0] = __float2bfloat16(f0.x); p.h[1] = __float2bfloat16(f0.y);
    p.h[2] = __float2bfloat16(f0.z); p.h[3] = __float2bfloat16(f0.w);
    p.h[4] = __float2bfloat16(f1.x); p.h[5] = __float2bfloat16(f1.y);
    p.h[6] = __float2bfloat16(f1.z); p.h[7] = __float2bfloat16(f1.w);
    *(uint4*)(Abf + e) = p.u4;
}

// ---------------------------------------------------------------------------
// Kernel 2: Bbf[n][k], n = u*4+g:  k<2048 ? W[g][u][k] : U[g][u][k-2048]
// ---------------------------------------------------------------------------
__global__ void convert_wu(const float* __restrict__ W,
                           const float* __restrict__ U,
                           __hip_bfloat16* __restrict__ Bbf) {
    const long long idx = (long long)blockIdx.x * blockDim.x + threadIdx.x;
    const long long e = idx * 8;
    const int n = (int)(e >> 12);
    const int k = (int)(e & 4095);
    const int u = n >> 2;
    const int g = n & 3;
    const float* src = (k < UNITS_DIM)
        ? (W + ((long long)g * UNITS_DIM + u) * UNITS_DIM + k)
        : (U + ((long long)g * UNITS_DIM + u) * UNITS_DIM + (k - UNITS_DIM));
    float4 f0 = ((const float4*)src)[0];
    float4 f1 = ((const float4*)src)[1];
    union { __hip_bfloat16 h[8]; uint4 u4; } p;
    p.h[0] = __float2bfloat16(f0.x); p.h[1] = __float2bfloat16(f0.y);
    p.h[2] = __float2bfloat16(f0.z); p.h[3] = __float2bfloat16(f0.w);
    p.h[4] = __float2bfloat16(f1.x); p.h[5] = __float2bfloat16(f1.y);
    p.h[6] = __float2bfloat16(f1.z); p.h[7] = __float2bfloat16(f1.w);
    *(uint4*)(Bbf + e) = p.u4;
}

// ---------------------------------------------------------------------------
// Kernel 3: bt-GEMM with XOR-swizzled LDS + fused LSTM epilogue.
//   Row stride in LDS is 64 bf16 = 32 dwords == 0 mod 32 banks, so the naive
//   layout gives 16-way conflicts on every ds_read_b128 (measured 1.0e8
//   SQ_LDS_BANK_CONFLICT). global_load_lds forbids per-lane LDS scatter, so
//   instead we permute the GLOBAL chunk each lane fetches:
//     LDS chunk c of row r holds global chunk  c ^ (r & 7)
//   Readers of (row r, global chunk g) index LDS chunk g ^ (r&7); each
//   16-lane quad-group then covers all 8 chunk-columns twice -> 2-way
//   aliasing, which is free (m136).
// ---------------------------------------------------------------------------
__global__ __launch_bounds__(256, 3) void lstm_gemm(
    const __hip_bfloat16* __restrict__ Wc,   // 8192 x 4096 (A operand)
    const __hip_bfloat16* __restrict__ Ac,   // 4096 x 4096 (B operand)
    const float* __restrict__ pre_c,         // 4096 x 2048
    float* __restrict__ out)                 // (2, 4096, 2048)
{
    __shared__ __hip_bfloat16 As[128 * 64];
    __shared__ __hip_bfloat16 Bs[128 * 64];

    const int tid  = threadIdx.x;
    const int lane = tid & 63;
    const int wave = tid >> 6;
    const int m_base = blockIdx.x * 128;
    const int n_base = blockIdx.y * 128;
    const int wm = (wave >> 1) * 64;
    const int wn = (wave & 1) * 64;
    const int l15 = lane & 15;
    const int lq  = lane >> 4;
    const int x7  = l15 & 7;            // read-side swizzle key (row & 7)

    f32x4 acc[4][4] = {};

    // staging: thread t -> row = t>>3 (+32/round), LDS chunk c = t&7.
    // Fetch global chunk c ^ (row&7) so LDS layout is XOR-swizzled.
    const int srow = tid >> 3;
    const int scol = (((tid & 7) ^ (srow & 7)) * 8);   // swizzled global col
    const __hip_bfloat16* wg = Wc + (size_t)(m_base + srow) * K_DIM + scol;
    const __hip_bfloat16* ag = Ac + (size_t)(n_base + srow) * K_DIM + scol;

    for (int k0 = 0; k0 < K_DIM; k0 += 64) {
#pragma unroll
        for (int r = 0; r < 4; ++r) {
            __builtin_amdgcn_global_load_lds(
                AS1C(wg + (size_t)(r * 32) * K_DIM + k0),
                AS3(As + r * 2048 + tid * 8), 16, 0, 0);
            __builtin_amdgcn_global_load_lds(
                AS1C(ag + (size_t)(r * 32) * K_DIM + k0),
                AS3(Bs + r * 2048 + tid * 8), 16, 0, 0);
        }
        __syncthreads();
#pragma unroll
        for (int ki = 0; ki < 2; ++ki) {
            const int ca = ((ki * 4 + lq) ^ x7) * 8;   // swizzled LDS chunk
            bf16x8 af[4], bfr[4];
#pragma unroll
            for (int mi = 0; mi < 4; ++mi)
                af[mi] = *(const bf16x8*)(As + (wm + mi * 16 + l15) * 64 + ca);
#pragma unroll
            for (int ni = 0; ni < 4; ++ni)
                bfr[ni] = *(const bf16x8*)(Bs + (wn + ni * 16 + l15) * 64 + ca);
#pragma unroll
            for (int mi = 0; mi < 4; ++mi)
#pragma unroll
                for (int ni = 0; ni < 4; ++ni)
                    acc[mi][ni] = __builtin_amdgcn_mfma_f32_16x16x32_bf16(
                        af[mi], bfr[ni], acc[mi][ni], 0, 0, 0);
        }
        __syncthreads();
    }

    // Fused LSTM epilogue — each lane's frag = (i,f,o,n~) for one (b,u)
#pragma unroll
    for (int mi = 0; mi < 4; ++mi) {
        const int u = ((m_base + wm + mi * 16) >> 2) + lq;
#pragma unroll
        for (int ni = 0; ni < 4; ++ni) {
            const int b = n_base + wn + ni * 16 + l15;
            f32x4 gv = acc[mi][ni];
            float i_t = fast_sigmoid(gv[0]);
            float f_t = fast_sigmoid(gv[1]);
            float o_t = fast_sigmoid(gv[2]);
            float n_t = fast_tanh(gv[3]);
            float pc  = pre_c[(size_t)b * UNITS_DIM + u];
            float c   = f_t * pc + i_t * n_t;
            float h   = o_t * fast_tanh(c);
            out[(size_t)b * UNITS_DIM + u] = h;
            out[(size_t)B_DIM * UNITS_DIM + (size_t)b * UNITS_DIM + u] = c;
        }
    }
}

extern "C" void kernel_launch(void* const* d_in, const int* in_sizes, int n_in,
                              void* d_out, int out_size, void* d_ws, size_t ws_size,
                              hipStream_t stream) {
    const float* pre_layer = (const float*)d_in[0];   // (2, 4096, 2048)
    const float* x         = (const float*)d_in[1];   // (4096, 2048)
    const float* W         = (const float*)d_in[2];   // (4, 2048, 2048)
    const float* U         = (const float*)d_in[3];   // (4, 2048, 2048)
    float* out = (float*)d_out;

    const float* pre_h = pre_layer;
    const float* pre_c = pre_layer + (size_t)B_DIM * UNITS_DIM;

    __hip_bfloat16* Abf = (__hip_bfloat16*)d_ws;                       // 32 MiB
    __hip_bfloat16* Bbf = (__hip_bfloat16*)((char*)d_ws +
                          (size_t)B_DIM * K_DIM * sizeof(__hip_bfloat16)); // 64 MiB

    convert_act<<<8192, 256, 0, stream>>>(pre_h, x, Abf);
    convert_wu<<<16384, 256, 0, stream>>>(W, U, Bbf);

    dim3 grid(M_DIM / 128, B_DIM / 128);   // (64, 32)
    lstm_gemm<<<grid, 256, 0, stream>>>(Bbf, Abf, pre_c, out);
}